// Round 1
// baseline (359.357 us; speedup 1.0000x reference)
//
#include <hip/hip_runtime.h>
#include <hip/hip_bf16.h>

typedef __attribute__((ext_vector_type(4))) float  f32x4;
typedef __attribute__((ext_vector_type(8))) short  short8;
typedef __attribute__((ext_vector_type(8))) unsigned short ushort8;
typedef __attribute__((ext_vector_type(4))) unsigned short u16x4;
typedef unsigned short u16;

__device__ __forceinline__ u16 f2bf(float f) {
    unsigned int u = __builtin_bit_cast(unsigned int, f);
    return (u16)((u + 0x7fffu + ((u >> 16) & 1u)) >> 16);
}

__device__ __forceinline__ f32x4 mfma16(short8 a, short8 b, f32x4 c) {
    return __builtin_amdgcn_mfma_f32_16x16x32_bf16(a, b, c, 0, 0, 0);
}

// ---------------- transpose + cast: W[K][N] f32 -> Wt[N][K] bf16 ----------------
__global__ __launch_bounds__(256) void tcast_kernel(const float* __restrict__ W,
                                                    u16* __restrict__ Wt,
                                                    int K, int N) {
    __shared__ float tile[32][33];
    const int tx = threadIdx.x & 31, ty = threadIdx.x >> 5; // ty 0..7
    const int c0 = blockIdx.x * 32;  // N
    const int r0 = blockIdx.y * 32;  // K
#pragma unroll
    for (int i = 0; i < 32; i += 8)
        tile[ty + i][tx] = W[(size_t)(r0 + ty + i) * N + c0 + tx];
    __syncthreads();
#pragma unroll
    for (int i = 0; i < 32; i += 8)
        Wt[(size_t)(c0 + ty + i) * K + r0 + tx] = f2bf(tile[tx][ty + i]);
}

// ---------------- LayerNorm: f32 [rows][1024] -> bf16, apply w,b ----------------
__global__ __launch_bounds__(256) void ln_kernel(const float* __restrict__ x,
                                                 const float* __restrict__ w,
                                                 const float* __restrict__ b,
                                                 u16* __restrict__ out) {
    const int row = blockIdx.x;
    const int tid = threadIdx.x;
    const float4 v = ((const float4*)(x + (size_t)row * 1024))[tid];
    float s1 = v.x + v.y + v.z + v.w;
    float s2 = v.x * v.x + v.y * v.y + v.z * v.z + v.w * v.w;
#pragma unroll
    for (int m = 1; m < 64; m <<= 1) { s1 += __shfl_xor(s1, m); s2 += __shfl_xor(s2, m); }
    __shared__ float red1[4], red2[4];
    const int wave = tid >> 6, lane = tid & 63;
    if (lane == 0) { red1[wave] = s1; red2[wave] = s2; }
    __syncthreads();
    s1 = red1[0] + red1[1] + red1[2] + red1[3];
    s2 = red2[0] + red2[1] + red2[2] + red2[3];
    const float mean = s1 * (1.0f / 1024.0f);
    const float var  = s2 * (1.0f / 1024.0f) - mean * mean;
    const float rstd = rsqrtf(var + 1e-5f);
    const float4 wv = ((const float4*)w)[tid];
    const float4 bv = ((const float4*)b)[tid];
    u16x4 o;
    o[0] = f2bf((v.x - mean) * rstd * wv.x + bv.x);
    o[1] = f2bf((v.y - mean) * rstd * wv.y + bv.y);
    o[2] = f2bf((v.z - mean) * rstd * wv.z + bv.z);
    o[3] = f2bf((v.w - mean) * rstd * wv.w + bv.w);
    *(u16x4*)(out + (size_t)row * 1024 + tid * 4) = o;
}

// ---------------- bf16 GEMM: C = A[M][K] @ Bt[N][K]^T  (+bias, +gelu, +res) -----
// 128x128 tile, BK=64, 4 waves (2x2), each wave 64x64 = 4x4 MFMA 16x16x32 frags.
template <int HAS_BIAS, int HAS_RES, int DO_GELU, int OUT_BF16>
__global__ __launch_bounds__(256) void gemm_kernel(const u16* __restrict__ A,
                                                   const u16* __restrict__ Bt,
                                                   const float* __restrict__ bias,
                                                   const float* __restrict__ res,
                                                   void* __restrict__ Cout,
                                                   int M, int N, int K) {
    constexpr int LDT = 72; // 64 + 8 pad (keeps 16B alignment, kills conflicts)
    __shared__ __align__(16) u16 As[128 * LDT];
    __shared__ __align__(16) u16 Bs[128 * LDT];
    const int tid = threadIdx.x;
    const int wave = tid >> 6, lane = tid & 63;
    const int wr = wave >> 1, wc = wave & 1;
    const int fq = lane >> 4, fr = lane & 15;
    const size_t bm = (size_t)blockIdx.y * 128, bn = (size_t)blockIdx.x * 128;

    f32x4 acc[4][4] = {};

    for (int k0 = 0; k0 < K; k0 += 64) {
#pragma unroll
        for (int i = 0; i < 4; i++) {
            const int task = tid + i * 256;
            const int r = task >> 3, seg = task & 7;
            ushort8 va = *(const ushort8*)(A + (bm + r) * (size_t)K + k0 + seg * 8);
            *(ushort8*)&As[r * LDT + seg * 8] = va;
            ushort8 vb = *(const ushort8*)(Bt + (bn + r) * (size_t)K + k0 + seg * 8);
            *(ushort8*)&Bs[r * LDT + seg * 8] = vb;
        }
        __syncthreads();
#pragma unroll
        for (int ks = 0; ks < 2; ks++) {
            short8 af[4], bf[4];
#pragma unroll
            for (int t = 0; t < 4; t++) {
                af[t] = *(const short8*)&As[(wr * 64 + t * 16 + fr) * LDT + ks * 32 + fq * 8];
                bf[t] = *(const short8*)&Bs[(wc * 64 + t * 16 + fr) * LDT + ks * 32 + fq * 8];
            }
#pragma unroll
            for (int mt = 0; mt < 4; mt++)
#pragma unroll
                for (int nt = 0; nt < 4; nt++)
                    acc[mt][nt] = mfma16(af[mt], bf[nt], acc[mt][nt]);
        }
        __syncthreads();
    }
    // epilogue: C[row][col], row = 16*mt + 4*fq + j, col = 16*nt + fr (verified layout)
#pragma unroll
    for (int mt = 0; mt < 4; mt++) {
#pragma unroll
        for (int nt = 0; nt < 4; nt++) {
            const size_t col = bn + wc * 64 + nt * 16 + fr;
            const float bb = HAS_BIAS ? bias[col] : 0.0f;
#pragma unroll
            for (int j = 0; j < 4; j++) {
                const size_t row = bm + wr * 64 + mt * 16 + fq * 4 + j;
                float v = acc[mt][nt][j] + bb;
                if (DO_GELU) v = 0.5f * v * (1.0f + erff(v * 0.70710678118f));
                if (HAS_RES) v += res[row * N + col];
                if (OUT_BF16) ((u16*)Cout)[row * N + col] = f2bf(v);
                else          ((float*)Cout)[row * N + col] = v;
            }
        }
    }
}

// ---------------- flash attention: qkv bf16 [4096][3072] -> O bf16 [4096][1024] --
// grid (B*H=32, N/64=32); 4 waves, each owns 16 query rows; KV tiles of 64.
__global__ __launch_bounds__(256) void attn_kernel(const u16* __restrict__ qkv,
                                                   u16* __restrict__ O) {
    const int bh = blockIdx.x;
    const int b = bh >> 4, h = bh & 15;
    const int qb = blockIdx.y;
    const int tid = threadIdx.x, wave = tid >> 6, lane = tid & 63;
    const int fq = lane >> 4, fr = lane & 15;
    __shared__ __align__(16) u16 Ks[64 * 72];
    __shared__ __align__(16) u16 Vt[64 * 72]; // transposed: Vt[d][key]
    __shared__ __align__(16) u16 Pl[4][16 * 72];

    const size_t base = (size_t)b * 2048 * 3072;
    const int q0 = qb * 64 + wave * 16;

    short8 qf[2];
#pragma unroll
    for (int ks = 0; ks < 2; ks++)
        qf[ks] = *(const short8*)(qkv + base + (size_t)(q0 + fr) * 3072 + h * 64 + ks * 32 + fq * 8);

    f32x4 accO[4] = {};
    float mrow[4], lrow[4];
#pragma unroll
    for (int j = 0; j < 4; j++) { mrow[j] = -1e30f; lrow[j] = 0.0f; }

    for (int kt = 0; kt < 32; kt++) {
        // stage K [key][d] (dc fastest for coalescing)
#pragma unroll
        for (int i = 0; i < 2; i++) {
            const int task = tid + i * 256;
            const int key = task >> 3, dc = task & 7;
            ushort8 kv = *(const ushort8*)(qkv + base + (size_t)(kt * 64 + key) * 3072 + 1024 + h * 64 + dc * 8);
            *(ushort8*)&Ks[key * 72 + dc * 8] = kv;
        }
        // stage V transposed (key fastest across lanes -> conflict-free LDS writes)
#pragma unroll
        for (int i = 0; i < 2; i++) {
            const int task = tid + i * 256;
            const int key = task & 63, dc = task >> 6;
            ushort8 vv = *(const ushort8*)(qkv + base + (size_t)(kt * 64 + key) * 3072 + 2048 + h * 64 + dc * 8);
#pragma unroll
            for (int j = 0; j < 8; j++) Vt[(dc * 8 + j) * 72 + key] = vv[j];
        }
        __syncthreads();

        // S = Q K^T * scale  (4 sub-tiles of 16 keys)
        f32x4 s[4];
#pragma unroll
        for (int nt = 0; nt < 4; nt++) {
            f32x4 a = {};
#pragma unroll
            for (int ks = 0; ks < 2; ks++) {
                short8 kf = *(const short8*)&Ks[(nt * 16 + fr) * 72 + ks * 32 + fq * 8];
                a = mfma16(qf[ks], kf, a);
            }
#pragma unroll
            for (int j = 0; j < 4; j++) s[nt][j] = a[j] * 0.125f;
        }
        // online softmax: row max over 4 tiles + 16 lanes
        float alpha[4];
#pragma unroll
        for (int j = 0; j < 4; j++) {
            float m = fmaxf(fmaxf(s[0][j], s[1][j]), fmaxf(s[2][j], s[3][j]));
            m = fmaxf(m, __shfl_xor(m, 1)); m = fmaxf(m, __shfl_xor(m, 2));
            m = fmaxf(m, __shfl_xor(m, 4)); m = fmaxf(m, __shfl_xor(m, 8));
            const float mn = fmaxf(mrow[j], m);
            alpha[j] = __expf(mrow[j] - mn);
            mrow[j] = mn;
        }
        float ls[4] = {0.f, 0.f, 0.f, 0.f};
#pragma unroll
        for (int nt = 0; nt < 4; nt++)
#pragma unroll
            for (int j = 0; j < 4; j++) {
                const float pij = __expf(s[nt][j] - mrow[j]);
                s[nt][j] = pij;
                ls[j] += pij;
            }
#pragma unroll
        for (int j = 0; j < 4; j++) {
            float t = ls[j];
            t += __shfl_xor(t, 1); t += __shfl_xor(t, 2);
            t += __shfl_xor(t, 4); t += __shfl_xor(t, 8);
            lrow[j] = lrow[j] * alpha[j] + t;
        }
#pragma unroll
        for (int dt = 0; dt < 4; dt++)
#pragma unroll
            for (int j = 0; j < 4; j++) accO[dt][j] *= alpha[j];
        // P: D-layout -> A-layout via per-wave LDS roundtrip
#pragma unroll
        for (int nt = 0; nt < 4; nt++)
#pragma unroll
            for (int j = 0; j < 4; j++)
                Pl[wave][(fq * 4 + j) * 72 + nt * 16 + fr] = f2bf(s[nt][j]);
        // O += P @ V
#pragma unroll
        for (int ks = 0; ks < 2; ks++) {
            short8 pf = *(const short8*)&Pl[wave][fr * 72 + ks * 32 + fq * 8];
#pragma unroll
            for (int dt = 0; dt < 4; dt++) {
                short8 vf = *(const short8*)&Vt[(dt * 16 + fr) * 72 + ks * 32 + fq * 8];
                accO[dt] = mfma16(pf, vf, accO[dt]);
            }
        }
        __syncthreads();
    }
#pragma unroll
    for (int dt = 0; dt < 4; dt++)
#pragma unroll
        for (int j = 0; j < 4; j++) {
            const float v = accO[dt][j] / lrow[j];
            O[(size_t)(b * 2048 + q0 + fq * 4 + j) * 1024 + h * 64 + dt * 16 + fr] = f2bf(v);
        }
}

extern "C" void kernel_launch(void* const* d_in, const int* in_sizes, int n_in,
                              void* d_out, int out_size, void* d_ws, size_t ws_size,
                              hipStream_t stream) {
    (void)in_sizes; (void)n_in; (void)out_size; (void)ws_size;
    const float* x     = (const float*)d_in[0];
    const float* ln1w  = (const float*)d_in[1];
    const float* ln1b  = (const float*)d_in[2];
    const float* qkvw  = (const float*)d_in[3];
    const float* projw = (const float*)d_in[4];
    const float* projb = (const float*)d_in[5];
    const float* ln2w  = (const float*)d_in[6];
    const float* ln2b  = (const float*)d_in[7];
    const float* fc1w  = (const float*)d_in[8];
    const float* fc1b  = (const float*)d_in[9];
    const float* fc2w  = (const float*)d_in[10];
    const float* fc2b  = (const float*)d_in[11];

    char* p = (char*)d_ws;
    auto alloc = [&](size_t bytes) { void* r = p; p += (bytes + 255) & ~(size_t)255; return r; };
    u16* wt_qkv  = (u16*)alloc(3072ull * 1024 * 2); // [3072][1024]
    u16* wt_proj = (u16*)alloc(1024ull * 1024 * 2); // [1024][1024]
    u16* wt_fc1  = (u16*)alloc(4096ull * 1024 * 2); // [4096][1024]
    u16* wt_fc2  = (u16*)alloc(1024ull * 4096 * 2); // [1024][4096]
    u16* h1      = (u16*)alloc(4096ull * 1024 * 2);
    u16* qkv     = (u16*)alloc(4096ull * 3072 * 2);
    u16* attn_o  = (u16*)alloc(4096ull * 1024 * 2);
    u16* h2      = (u16*)alloc(4096ull * 1024 * 2);
    u16* mlp_h   = (u16*)alloc(4096ull * 4096 * 2);
    float* x1 = (float*)d_out; // post-attention residual lives in d_out

    // weights -> bf16 transposed
    tcast_kernel<<<dim3(96, 32),  256, 0, stream>>>(qkvw,  wt_qkv, 1024, 3072);
    tcast_kernel<<<dim3(32, 32),  256, 0, stream>>>(projw, wt_proj, 1024, 1024);
    tcast_kernel<<<dim3(128, 32), 256, 0, stream>>>(fc1w,  wt_fc1, 1024, 4096);
    tcast_kernel<<<dim3(32, 128), 256, 0, stream>>>(fc2w,  wt_fc2, 4096, 1024);

    // attention sub-block
    ln_kernel<<<4096, 256, 0, stream>>>(x, ln1w, ln1b, h1);
    gemm_kernel<0, 0, 0, 1><<<dim3(24, 32), 256, 0, stream>>>(h1, wt_qkv, nullptr, nullptr, qkv, 4096, 3072, 1024);
    attn_kernel<<<dim3(32, 32), 256, 0, stream>>>(qkv, attn_o);
    gemm_kernel<1, 1, 0, 0><<<dim3(8, 32), 256, 0, stream>>>(attn_o, wt_proj, projb, x, x1, 4096, 1024, 1024);

    // MLP sub-block
    ln_kernel<<<4096, 256, 0, stream>>>(x1, ln2w, ln2b, h2);
    gemm_kernel<1, 0, 1, 1><<<dim3(32, 32), 256, 0, stream>>>(h2, wt_fc1, fc1b, nullptr, mlp_h, 4096, 4096, 1024);
    gemm_kernel<1, 1, 0, 0><<<dim3(8, 32), 256, 0, stream>>>(mlp_h, wt_fc2, fc2b, x1, d_out, 4096, 1024, 4096);
}